// Round 10
// baseline (2785.889 us; speedup 1.0000x reference)
//
#include <hip/hip_runtime.h>
#include <hip/hip_bf16.h>
#include <stdint.h>

typedef __attribute__((ext_vector_type(4))) float f32x4;
typedef __attribute__((ext_vector_type(8))) short bf16x8;

// ---- workspace layout (bytes) ----
#define WS_XBF   0u          // x gathered, bf16 [S=512][B=32][E=256]          = 8388608
#define WS_WIR   8388608u    // Wi rows bf16 [2048][256] (identity order)      = 1048576
#define WS_BIAS  9437184u    // bi+bh f32 [2048]                               = 8192
#define WS_PRE   9445376u    // pre bf16 [dir][s][bh][w][lane][32]             = 67108864
#define WS_HALL  76554240u   // h states bf16 [2][513 t][32 b][256 h]          = 16809984
#define WS_EMIS  93368320u   // emissions f32 [32 b][512 s][16 t]              = 1048576
#define WS_CHK   94416896u   // CRF chunk mats f32 [32 b][32 c][16][16]        = 1048576
#define WS_OP    93368320u   // o-gate packed frags bf16 [dir][w][hg][kt][l][8] = 262144
                             // aliases WS_EMIS: written k_prep, read k_rec, dead before k_emis

__device__ __forceinline__ unsigned short f2bf(float x) {
    union { float f; unsigned int u; } v; v.f = x;
    return (unsigned short)((v.u + 0x7FFFu + ((v.u >> 16) & 1u)) >> 16);
}
__device__ __forceinline__ float bf2f(unsigned short b) {
    union { float f; unsigned int u; } v; v.u = ((unsigned int)b) << 16; return v.f;
}
__device__ __forceinline__ float bfh(unsigned int w, int hi) {
    return bf2f((unsigned short)(hi ? (w >> 16) : (w & 0xffff)));
}
__device__ __forceinline__ unsigned int pack2(float a, float b) {
    return (unsigned int)f2bf(a) | ((unsigned int)f2bf(b) << 16);
}
__device__ __forceinline__ float sigf(float x)  { return 1.0f / (1.0f + __expf(-x)); }
__device__ __forceinline__ float tanhf_(float x){ return 1.0f - 2.0f / (__expf(2.0f * x) + 1.0f); }

// ============ kernel 1: gather x -> bf16, Wi -> bf16 (identity rows), biases, o-gate pack ============
__global__ __launch_bounds__(256) void k_prep(
    const int* __restrict__ tokens, const float* __restrict__ embed,
    const float* __restrict__ Wi_f, const float* __restrict__ Wi_b,
    const float* __restrict__ bi_f, const float* __restrict__ bh_f,
    const float* __restrict__ bi_b, const float* __restrict__ bh_b,
    const float* __restrict__ Wh_f, const float* __restrict__ Wh_b,
    char* __restrict__ ws)
{
    int blk = blockIdx.x, tid = threadIdx.x;
    unsigned short* xbf  = (unsigned short*)(ws + WS_XBF);
    unsigned short* wir  = (unsigned short*)(ws + WS_WIR);
    float* biasr         = (float*)(ws + WS_BIAS);
    if (blk < 2048) {                       // x gather: 8 rows/block
        int rr = tid >> 5, cc = tid & 31;
        int r = blk * 8 + rr;               // r = s*32+b
        int s = r >> 5, b = r & 31;
        int tok = tokens[b * 512 + s];
        int k = cc * 8;
        const float* src = embed + (size_t)tok * 256 + k;
        float4 a = *(const float4*)src;
        float4 c = *(const float4*)(src + 4);
        uint4 o; o.x = pack2(a.x, a.y); o.y = pack2(a.z, a.w);
        o.z = pack2(c.x, c.y); o.w = pack2(c.z, c.w);
        *(uint4*)(xbf + (size_t)r * 256 + k) = o;
    } else if (blk < 2304) {                // Wi rows (identity: rowp = dir*1024 + g*256 + hid)
        int rr = tid >> 5, cc = tid & 31;
        int rowp = (blk - 2048) * 8 + rr;   // 0..2047
        int dir = rowp >> 10, srow = rowp & 1023;
        const float* W = dir ? Wi_b : Wi_f;
        int k = cc * 8;
        const float* src = W + (size_t)srow * 256 + k;
        float4 a = *(const float4*)src;
        float4 c = *(const float4*)(src + 4);
        uint4 o; o.x = pack2(a.x, a.y); o.y = pack2(a.z, a.w);
        o.z = pack2(c.x, c.y); o.w = pack2(c.z, c.w);
        *(uint4*)(wir + (size_t)rowp * 256 + k) = o;
        if (cc == 0)
            biasr[rowp] = dir ? (bi_b[srow] + bh_b[srow]) : (bi_f[srow] + bh_f[srow]);
    } else {                                // blk 2304..2335: pack o-gate B-frags (lane-contiguous)
        unsigned short* opk = (unsigned short*)(ws + WS_OP);
        int base = (blk - 2304) * 256 + tid;       // 0..8191
        #pragma unroll
        for (int i = 0; i < 16; ++i) {
            int u = base * 16 + i;                 // 0..131071
            int j = u & 7, lq = (u >> 3) & 63, kt = (u >> 9) & 7;
            int hg = (u >> 12) & 1, wv = (u >> 13) & 7, dr = (u >> 16) & 1;
            int colp = lq & 15, quadp = lq >> 4;
            const float* W = dr ? Wh_b : Wh_f;
            float x = W[(size_t)(768 + wv * 32 + hg * 16 + colp) * 256 + kt * 32 + quadp * 8 + j];
            opk[u] = f2bf(x);
        }
    }
}

// ============ kernel 2: pre = x*Wi^T + bias, lane-private layout for k_rec ============
__global__ __launch_bounds__(256) void k_pregemm(char* __restrict__ ws)
{
    __shared__ unsigned short Asb[128 * 136];
    __shared__ unsigned short Bsb[64 * 136];
    const unsigned short* xbf = (const unsigned short*)(ws + WS_XBF);
    const unsigned short* wir = (const unsigned short*)(ws + WS_WIR);
    const float* biasr        = (const float*)(ws + WS_BIAS);
    unsigned short* pre       = (unsigned short*)(ws + WS_PRE);
    int blk = blockIdx.x, tid = threadIdx.x;
    int mb = blk >> 5, nb = blk & 31;
    int Mbase = mb * 128, Nbase = nb * 64;
    int w = tid >> 6, l = tid & 63, col = l & 15, quad = l >> 4;
    f32x4 acc[4][2];
    #pragma unroll
    for (int a = 0; a < 4; ++a)
        #pragma unroll
        for (int b = 0; b < 2; ++b) acc[a][b] = (f32x4){0.f, 0.f, 0.f, 0.f};

    for (int kh = 0; kh < 2; ++kh) {
        __syncthreads();
        #pragma unroll
        for (int i = 0; i < 8; ++i) {       // A half-tile 128x128 bf16
            int c = tid + i * 256;
            int row = c >> 4, c16 = c & 15;
            uint4 v = *(const uint4*)(xbf + ((size_t)(Mbase + row) * 256 + kh * 128 + c16 * 8));
            *(uint4*)(Asb + row * 136 + c16 * 8) = v;
        }
        #pragma unroll
        for (int i = 0; i < 4; ++i) {       // B half-tile 64x128 bf16
            int c = tid + i * 256;
            int row = c >> 4, c16 = c & 15;
            uint4 v = *(const uint4*)(wir + ((size_t)(Nbase + row) * 256 + kh * 128 + c16 * 8));
            *(uint4*)(Bsb + row * 136 + c16 * 8) = v;
        }
        __syncthreads();
        int mhalf = w >> 1, nh = w & 1;
        #pragma unroll
        for (int kt = 0; kt < 4; ++kt) {
            bf16x8 bfr[2];
            #pragma unroll
            for (int nn = 0; nn < 2; ++nn)
                bfr[nn] = *(const bf16x8*)(Bsb + (16 * (nh * 2 + nn) + col) * 136 + kt * 32 + quad * 8);
            #pragma unroll
            for (int mm = 0; mm < 4; ++mm) {
                bf16x8 afr = *(const bf16x8*)(Asb + (16 * (mhalf * 4 + mm) + col) * 136 + kt * 32 + quad * 8);
                #pragma unroll
                for (int nn = 0; nn < 2; ++nn)
                    acc[mm][nn] = __builtin_amdgcn_mfma_f32_16x16x32_bf16(afr, bfr[nn], acc[mm][nn], 0, 0, 0);
            }
        }
    }
    // epilogue: + bias -> bf16 -> preP[dir][s][bh][wr][lane][v], v = hg*16 + g*4 + r
    #pragma unroll
    for (int mm = 0; mm < 4; ++mm) {
        int m_t = (w >> 1) * 4 + mm;
        int s = (Mbase >> 5) + (m_t >> 1);
        int bh = m_t & 1;
        #pragma unroll
        for (int nn = 0; nn < 2; ++nn) {
            int ncol = Nbase + 16 * ((w & 1) * 2 + nn) + col;
            int dir = ncol >> 10, q = ncol & 1023;
            int g = q >> 8, hid = q & 255;
            int wr = hid >> 5, hg = (hid >> 4) & 1;
            float bv = biasr[ncol];
            f32x4 a = acc[mm][nn];
            uint2 o;
            o.x = pack2(a[0] + bv, a[1] + bv);
            o.y = pack2(a[2] + bv, a[3] + bv);
            size_t off = (((((size_t)dir * 512 + s) * 2 + bh) * 8 + wr) * 64 + l) * 32 + hg * 16 + g * 4;
            *(uint2*)(pre + off) = o;
        }
    }
}

// ============ kernel 3: batch-split bidirectional LSTM recurrence (NO cross-block comm) ============
// grid = 4: dir = blk>>1, batch-half bh = blk&1 (16 batch rows, M=16 full density).
// h feedback is block-LOCAL: LDS parity buffer + one __syncthreads per step. No atomics.
// Weights: gates i,f,g resident in VGPRs (192/lane); o-gate streamed from L2 (prepacked oP).
__global__ __launch_bounds__(512, 2) void k_rec(
    const float* __restrict__ Wh_f, const float* __restrict__ Wh_b, char* __restrict__ ws)
{
    __shared__ unsigned short hb[2][16 * 264];   // [parity][16 batch rows][256+8 pad]
    int blk = blockIdx.x, tid = threadIdx.x;
    int dir = blk >> 1, bh = blk & 1;
    int w = tid >> 6, l = tid & 63, col = l & 15, quad = l >> 4;
    const float* Wh = dir ? Wh_b : Wh_f;
    const unsigned short* pre = (const unsigned short*)(ws + WS_PRE);
    const unsigned short* opk = (const unsigned short*)(ws + WS_OP);
    unsigned short* hall      = (unsigned short*)(ws + WS_HALL);

    // resident weights: gates i(0), f(1), g(2); rows g*256 + w*32 + hg*16 + col
    bf16x8 wf[3][2][8];
    #pragma unroll
    for (int g = 0; g < 3; ++g)
        #pragma unroll
        for (int hg = 0; hg < 2; ++hg) {
            int nrow = g * 256 + w * 32 + hg * 16 + col;
            #pragma unroll
            for (int kt = 0; kt < 8; ++kt) {
                const float* src = Wh + (size_t)nrow * 256 + kt * 32 + quad * 8;
                float4 x0 = *(const float4*)src;
                float4 x1 = *(const float4*)(src + 4);
                bf16x8 f;
                f[0] = (short)f2bf(x0.x); f[1] = (short)f2bf(x0.y);
                f[2] = (short)f2bf(x0.z); f[3] = (short)f2bf(x0.w);
                f[4] = (short)f2bf(x1.x); f[5] = (short)f2bf(x1.y);
                f[6] = (short)f2bf(x1.z); f[7] = (short)f2bf(x1.w);
                wf[g][hg][kt] = f;
            }
        }
    // h(0) = 0
    for (int u = tid; u < 2112; u += 512) ((unsigned int*)hb[0])[u] = 0;
    __syncthreads();

    float cst[8] = {0.f, 0.f, 0.f, 0.f, 0.f, 0.f, 0.f, 0.f};
    size_t hallbase = (size_t)dir * 513 * 8192;   // ushort units

    for (int st = 0; st < 512; ++st) {
        int s = dir ? (511 - st) : st;
        const unsigned short* prl = pre + (((((size_t)dir * 512 + s) * 2 + bh) * 8 + w) * 64 + l) * 32;
        const unsigned short* cur = hb[st & 1];
        unsigned short* nxt = hb[(st + 1) & 1];
        size_t gb = hallbase + (size_t)(st + 1) * 8192 + (size_t)(bh * 16) * 256 + w * 32 + col;

        #pragma unroll
        for (int hg = 0; hg < 2; ++hg) {
            f32x4 acc[4];
            #pragma unroll
            for (int g = 0; g < 4; ++g) acc[g] = (f32x4){0.f, 0.f, 0.f, 0.f};
            #pragma unroll
            for (int kt = 0; kt < 8; ++kt) {
                bf16x8 af = *(const bf16x8*)(cur + col * 264 + kt * 32 + quad * 8);
                bf16x8 of = *(const bf16x8*)(opk + ((((size_t)dir * 8 + w) * 2 + hg) * 8 + kt) * 512
                                                   + (size_t)l * 8);
                acc[0] = __builtin_amdgcn_mfma_f32_16x16x32_bf16(af, wf[0][hg][kt], acc[0], 0, 0, 0);
                acc[1] = __builtin_amdgcn_mfma_f32_16x16x32_bf16(af, wf[1][hg][kt], acc[1], 0, 0, 0);
                acc[2] = __builtin_amdgcn_mfma_f32_16x16x32_bf16(af, wf[2][hg][kt], acc[2], 0, 0, 0);
                acc[3] = __builtin_amdgcn_mfma_f32_16x16x32_bf16(af, of,            acc[3], 0, 0, 0);
            }
            // pre half: 16 bf16 at v = hg*16 + g*4 + r  -> word g*2 + (r>>1), half r&1
            uint4 pa = *(const uint4*)(prl + hg * 16);
            uint4 pb = *(const uint4*)(prl + hg * 16 + 8);
            unsigned int pw[8] = {pa.x, pa.y, pa.z, pa.w, pb.x, pb.y, pb.z, pb.w};
            #pragma unroll
            for (int r = 0; r < 4; ++r) {
                float zi = acc[0][r] + bfh(pw[0 + (r >> 1)], r & 1);
                float zf = acc[1][r] + bfh(pw[2 + (r >> 1)], r & 1);
                float zg = acc[2][r] + bfh(pw[4 + (r >> 1)], r & 1);
                float zo = acc[3][r] + bfh(pw[6 + (r >> 1)], r & 1);
                int ci = hg * 4 + r;
                float c_ = sigf(zf) * cst[ci] + sigf(zi) * tanhf_(zg);
                cst[ci] = c_;
                unsigned short hv = f2bf(sigf(zo) * tanhf_(c_));
                nxt[(quad * 4 + r) * 264 + w * 32 + hg * 16 + col] = hv;           // feedback
                hall[gb + (size_t)(quad * 4 + r) * 256 + hg * 16] = hv;            // history
            }
        }
        __syncthreads();   // parity handoff (single barrier per step)
    }
}

// ============ kernel 4: emissions e[b][s][t] = [hf|hb] . Wt[t] + bt ============
__global__ __launch_bounds__(256) void k_emis(
    const float* __restrict__ Wt, const float* __restrict__ bt, char* __restrict__ ws)
{
    __shared__ float WtL[16 * 528];
    __shared__ unsigned short hrow[16 * 536];
    __shared__ float btL[16];
    int blk = blockIdx.x, tid = threadIdx.x;
    int sbb = blk * 16;
    int s = sbb >> 5, bbase = sbb & 31;     // 16 batch rows per block, fixed s
    const unsigned short* hall = (const unsigned short*)(ws + WS_HALL);
    float* emis = (float*)(ws + WS_EMIS);
    #pragma unroll
    for (int i = 0; i < 8; ++i) {           // Wt 16x512 f32 -> LDS
        int c = tid + i * 256;
        int trow = c >> 7, c128 = c & 127;
        float4 v = *(const float4*)(Wt + (size_t)trow * 512 + c128 * 4);
        *(float4*)(WtL + trow * 528 + c128 * 4) = v;
    }
    #pragma unroll
    for (int i = 0; i < 4; ++i) {           // h rows: [i][0..255]=hf(s), [i][256..511]=hb(s)
        int c = tid + i * 256;
        int row = c >> 6, c6 = c & 63, half = c6 >> 5, c16 = c6 & 31;
        size_t base = half == 0 ? (size_t)(s + 1) * 8192 : ((size_t)513 + (512 - s)) * 8192;
        uint4 v = *(const uint4*)(hall + base + (size_t)(bbase + row) * 256 + c16 * 8);
        *(uint4*)(hrow + row * 536 + half * 256 + c16 * 8) = v;
    }
    if (tid < 16) btL[tid] = bt[tid];
    __syncthreads();
    int t = tid >> 4, i = tid & 15;
    float acc = btL[t];
    const float* wrow = WtL + t * 528;
    const unsigned short* hr = hrow + i * 536;
    #pragma unroll 8
    for (int k = 0; k < 512; k += 4) {
        uint2 hu = *(const uint2*)(hr + k);
        float4 wv = *(const float4*)(wrow + k);
        acc += bf2f((unsigned short)(hu.x & 0xffff)) * wv.x
             + bf2f((unsigned short)(hu.x >> 16))    * wv.y
             + bf2f((unsigned short)(hu.y & 0xffff)) * wv.z
             + bf2f((unsigned short)(hu.y >> 16))    * wv.w;
    }
    emis[((size_t)(bbase + i) * 512 + s) * 16 + t] = acc;
}

// ============ kernel 5: CRF chunk products (log-semiring, associative) ============
__global__ __launch_bounds__(256) void k_crfc(const float* __restrict__ trans, char* __restrict__ ws)
{
    __shared__ float trL[16 * 17];
    __shared__ float est[16 * 16];
    __shared__ float Pb[2][16 * 17];
    int blk = blockIdx.x, tid = threadIdx.x;
    int b = blk >> 5, c = blk & 31;
    int t = tid >> 4, p = tid & 15;
    const float* emis = (const float*)(ws + WS_EMIS);
    float* chk = (float*)(ws + WS_CHK);
    trL[t * 17 + p] = trans[t * 16 + p];
    est[t * 16 + p] = emis[((size_t)b * 512 + c * 16 + t) * 16 + p];
    __syncthreads();
    float tr[16];
    #pragma unroll
    for (int q = 0; q < 16; ++q) tr[q] = trL[t * 17 + q];
    float out = trL[t * 17 + p] + est[0 * 16 + t];
    Pb[0][t * 17 + p] = out;
    __syncthreads();
    int cur = 0;
    for (int si = 1; si < 16; ++si) {
        float v[16]; float mx = -3.0e38f;
        #pragma unroll
        for (int q = 0; q < 16; ++q) { v[q] = tr[q] + Pb[cur][q * 17 + p]; mx = fmaxf(mx, v[q]); }
        float ss = 0.f;
        #pragma unroll
        for (int q = 0; q < 16; ++q) ss += __expf(v[q] - mx);
        out = est[si * 16 + t] + mx + __logf(ss);
        Pb[1 - cur][t * 17 + p] = out;
        __syncthreads();
        cur = 1 - cur;
    }
    chk[(size_t)(b * 32 + c) * 256 + t * 16 + p] = out;
}

// ============ kernel 6: fold 32 chunk matrices per batch, apply alpha0/stop, emit log_Z ============
__global__ __launch_bounds__(256) void k_crff(
    const float* __restrict__ trans, char* __restrict__ ws, float* __restrict__ out)
{
    __shared__ float Cst[16 * 17];
    __shared__ float Pb[2][16 * 17];
    __shared__ float af[16];
    int b = blockIdx.x, tid = threadIdx.x;
    int t = tid >> 4, p = tid & 15;
    const float* chk = (const float*)(ws + WS_CHK);
    Pb[0][t * 17 + p] = chk[(size_t)(b * 32) * 256 + t * 16 + p];
    __syncthreads();
    int cur = 0;
    for (int ci = 1; ci < 32; ++ci) {
        Cst[t * 17 + p] = chk[(size_t)(b * 32 + ci) * 256 + t * 16 + p];
        __syncthreads();
        float v[16]; float mx = -3.0e38f;
        #pragma unroll
        for (int q = 0; q < 16; ++q) { v[q] = Cst[t * 17 + q] + Pb[cur][q * 17 + p]; mx = fmaxf(mx, v[q]); }
        float ss = 0.f;
        #pragma unroll
        for (int q = 0; q < 16; ++q) ss += __expf(v[q] - mx);
        float outv = mx + __logf(ss);
        Pb[1 - cur][t * 17 + p] = outv;
        __syncthreads();
        cur = 1 - cur;
    }
    float vfin = Pb[cur][t * 17 + p] + ((p == 14) ? 0.0f : -10000.0f);  // alpha0: START=14
    Cst[t * 17 + p] = vfin;
    __syncthreads();
    if (tid < 16) {
        float mx = -3.0e38f;
        for (int q = 0; q < 16; ++q) mx = fmaxf(mx, Cst[tid * 17 + q]);
        float ss = 0.f;
        for (int q = 0; q < 16; ++q) ss += __expf(Cst[tid * 17 + q] - mx);
        af[tid] = mx + __logf(ss) + trans[15 * 16 + tid];               // STOP=15
    }
    __syncthreads();
    if (tid == 0) {
        float mx = -3.0e38f;
        for (int q = 0; q < 16; ++q) mx = fmaxf(mx, af[q]);
        float ss = 0.f;
        for (int q = 0; q < 16; ++q) ss += __expf(af[q] - mx);
        out[b] = mx + __logf(ss);
    }
}

extern "C" void kernel_launch(void* const* d_in, const int* in_sizes, int n_in,
                              void* d_out, int out_size, void* d_ws, size_t ws_size,
                              hipStream_t stream)
{
    const int*   tokens = (const int*)d_in[0];
    const float* embed  = (const float*)d_in[1];
    const float* Wi_f   = (const float*)d_in[2];
    const float* Wh_f   = (const float*)d_in[3];
    const float* bi_f   = (const float*)d_in[4];
    const float* bh_f   = (const float*)d_in[5];
    const float* Wi_b   = (const float*)d_in[6];
    const float* Wh_b   = (const float*)d_in[7];
    const float* bi_b   = (const float*)d_in[8];
    const float* bh_b   = (const float*)d_in[9];
    const float* Wt     = (const float*)d_in[10];
    const float* bt     = (const float*)d_in[11];
    const float* trans  = (const float*)d_in[12];
    char* ws = (char*)d_ws;
    float* out = (float*)d_out;

    hipLaunchKernelGGL(k_prep, dim3(2336), dim3(256), 0, stream,
                       tokens, embed, Wi_f, Wi_b, bi_f, bh_f, bi_b, bh_b, Wh_f, Wh_b, ws);
    hipLaunchKernelGGL(k_pregemm, dim3(4096), dim3(256), 0, stream, ws);
    hipLaunchKernelGGL(k_rec, dim3(4), dim3(512), 0, stream, Wh_f, Wh_b, ws);
    hipLaunchKernelGGL(k_emis, dim3(1024), dim3(256), 0, stream, Wt, bt, ws);
    hipLaunchKernelGGL(k_crfc, dim3(1024), dim3(256), 0, stream, trans, ws);
    hipLaunchKernelGGL(k_crff, dim3(32), dim3(256), 0, stream, trans, ws, out);
}